// Round 2
// baseline (11851.009 us; speedup 1.0000x reference)
//
#include <hip/hip_runtime.h>

typedef unsigned int u32;
typedef unsigned short u16;
typedef __attribute__((ext_vector_type(8))) short short8;
typedef __attribute__((ext_vector_type(4))) float floatx4;

#define TT 1024
#define KX 64        // padded x-input dim (43 -> 64)
#define KTOT 320     // KX + H (v1 fallback)
#define XH_S 328     // v1 fallback LDS stride
#define BIN_OFF 6553600
#define ACT_OFF 7864320

// scan2 fragment split: per wave 64 frags (8 kt x 8 tiles), F = kt*8+tile
#define F_REG 40     // F 0..39  register-resident
#define F_LDS 18     // F 40..57 LDS-resident
#define F_STR 6      // F 58..63 streamed from L2 each step

__device__ __forceinline__ u16 f2b(float f) {
  u32 u = __builtin_bit_cast(u32, f);
  u += 0x7fffu + ((u >> 16) & 1u);
  return (u16)(u >> 16);
}
__device__ __forceinline__ float b2f(u16 v) {
  return __builtin_bit_cast(float, ((u32)v) << 16);
}
__device__ __forceinline__ float sigmf(float x) { return 1.0f / (1.0f + __expf(-x)); }
__device__ __forceinline__ float tanhfast(float x) {
  x = fminf(x, 15.0f);
  float e = __expf(2.0f * x);
  return (e - 1.0f) / (e + 1.0f);
}

// ---------------- shared prep ----------------

// bias = b_ih + b_hh.  grid 4 x 256
__global__ void k_prep_bias(const float* __restrict__ a, const float* __restrict__ b,
                            float* __restrict__ o) {
  int i = blockIdx.x * 256 + threadIdx.x;
  o[i] = a[i] + b[i];
}
// W_afc1 (256x256) and W_aout padded to 16x256.  grid 272 x 256
__global__ void k_prep_afc(const float* __restrict__ wafc1, const float* __restrict__ waout,
                           u16* __restrict__ ob1, u16* __restrict__ ob2) {
  int r = blockIdx.x, k = threadIdx.x;
  if (r < 256) ob1[r * 256 + k] = f2b(wafc1[r * 256 + k]);
  else {
    int y = r - 256;
    ob2[y * 256 + k] = f2b(y < 8 ? waout[y * 256 + k] : 0.f);
  }
}
// Wcb[64][288]: rows 0..49 W_cont, 50..59 W_bin.  grid 64 x 288
__global__ void k_prep_wcb(const float* __restrict__ wcont, const float* __restrict__ wbin,
                           u16* __restrict__ o) {
  int nrow = blockIdx.x, k = threadIdx.x;
  float v = 0.f;
  if (k < 264) {
    if (nrow < 50) v = wcont[nrow * 264 + k];
    else if (nrow < 60) v = wbin[(nrow - 50) * 264 + k];
  }
  o[nrow * 288 + k] = f2b(v);
}

// ---------------- xg-path prep ----------------

// whhf frag-order: [(wave*64+F)*64+lane]*8+j = bf16 W_hh[n][k]
// tile=F&7 (g=tile>>1, ht=tile&1), kt=F>>3; n=g*256+wave*32+ht*16+(lane&15),
// k=kt*32+(lane>>4)*8+j.  grid 1024 x 256
__global__ void k_prep_whhf(const float* __restrict__ whh, u16* __restrict__ o) {
  u32 idx = blockIdx.x * 256 + threadIdx.x;   // < 2^18
  int j = idx & 7, lane = (idx >> 3) & 63, F = (idx >> 9) & 63, wave = idx >> 15;
  int tile = F & 7, kt = F >> 3;
  int n = (tile >> 1) * 256 + wave * 32 + (tile & 1) * 16 + (lane & 15);
  int k = kt * 32 + (lane >> 4) * 8 + j;
  o[idx] = f2b(whh[n * 256 + k]);
}
// wihp [1024][64] bf16 padded W_ih.  grid 256 x 256
__global__ void k_prep_wihp(const float* __restrict__ wih, u16* __restrict__ o) {
  u32 idx = blockIdx.x * 256 + threadIdx.x;   // < 65536
  int n = idx >> 6, d = idx & 63;
  o[idx] = f2b(d < 43 ? wih[n * 43 + d] : 0.f);
}

// xg GEMM: xg = xin(padded 64) @ W_ihp^T + bias, written bf16 in C-frag order:
// xgf[(((b'*1024+t)*8 + wave)*64 + lane)*32 + tile*4 + rr]
// grid 8192 (= b'*1024 + t), 512 threads (8 waves).
__global__ __launch_bounds__(512, 4)
void k_xg(const float* __restrict__ x, const u16* __restrict__ wihp,
          const float* __restrict__ bias, u16* __restrict__ xgf) {
  __shared__ u16 a_sh[16 * 64];     // swizzled: chunk c stored at c^(m&7)
  __shared__ float sbias[1024];
  const int tid = threadIdx.x;
  const int wave = tid >> 6, lane = tid & 63;
  const int l15 = lane & 15, kq = lane >> 4;
  const int bp = blockIdx.x >> 10;          // batch block 0..7
  const int t = blockIdx.x & 1023;

  sbias[tid] = bias[tid];
  sbias[tid + 512] = bias[tid + 512];
  {
    int e = tid * 2;                        // element pair, d even
    int m = e >> 6, d = e & 63;
    size_t bt = (size_t)(bp * 16 + m) * TT + t;
    float v0 = 0.f, v1 = 0.f;
    if (d < 35) v0 = x[bt * 43 + d];
    else if (d < 43 && t > 0) v0 = x[(bt - 1) * 43 + d];
    int d1 = d + 1;
    if (d1 < 35) v1 = x[bt * 43 + d1];
    else if (d1 < 43 && t > 0) v1 = x[(bt - 1) * 43 + d1];
    u32 pk = (u32)f2b(v0) | ((u32)f2b(v1) << 16);
    int chunk = d >> 3;
    *(u32*)&a_sh[m * 64 + (((chunk ^ (m & 7)) << 3) + (d & 7))] = pk;
  }
  __syncthreads();

  floatx4 acc[8];
#pragma unroll
  for (int tile = 0; tile < 8; ++tile) acc[tile] = (floatx4){0.f, 0.f, 0.f, 0.f};
#pragma unroll
  for (int kt = 0; kt < 2; ++kt) {
    short8 afr = *(const short8*)&a_sh[l15 * 64 + (((kt * 4 + kq) ^ (l15 & 7)) << 3)];
#pragma unroll
    for (int tile = 0; tile < 8; ++tile) {
      int n = (tile >> 1) * 256 + wave * 32 + (tile & 1) * 16 + l15;
      short8 bfr = *(const short8*)(wihp + n * 64 + kt * 32 + kq * 8);
      acc[tile] = __builtin_amdgcn_mfma_f32_16x16x32_bf16(afr, bfr, acc[tile], 0, 0, 0);
    }
  }
  // epilogue: + bias, pack 32 bf16 cells (cell = tile*4+rr)
  u16 cells[32];
#pragma unroll
  for (int tile = 0; tile < 8; ++tile) {
    int n = (tile >> 1) * 256 + wave * 32 + (tile & 1) * 16 + l15;
    float bb = sbias[n];
#pragma unroll
    for (int rr = 0; rr < 4; ++rr) cells[tile * 4 + rr] = f2b(acc[tile][rr] + bb);
  }
  u16* op = xgf + (((size_t)blockIdx.x * 8 + wave) * 64 + lane) * 32;
#pragma unroll
  for (int p = 0; p < 4; ++p) {
    short8 v;
#pragma unroll
    for (int q = 0; q < 8; ++q) v[q] = (short)cells[p * 8 + q];
    *(short8*)(op + p * 8) = v;
  }
}

// ---------------- LSTM scan v2 ----------------
// 8 WGs x 512 threads (8 waves, 2/SIMD, 256 VGPR cap). WG owns 16 batch rows.
// gates(16x1024) = h(16x256) @ W_hh^T + xg_t. W_hh frags: 40 in VGPR, 18 in LDS,
// 6 streamed from L2. h tile in LDS, XOR-chunk-swizzled (2-way banks = free).
__global__ __launch_bounds__(512, 2)
void k_scan2(const u16* __restrict__ whhf, const u16* __restrict__ xgf,
             u16* __restrict__ hs) {
  __shared__ u16 wlds[8 * F_LDS * 512];   // 147456 B: [wave][frag][lane*8]
  __shared__ u16 hsw[16 * 256];           // 8192 B swizzled h tile
  const int tid = threadIdx.x;
  const int wave = tid >> 6, lane = tid & 63;
  const int l15 = lane & 15, kq = lane >> 4;
  const int b0 = blockIdx.x << 4;

  for (int i = tid; i < 4096; i += 512) hsw[i] = 0;

  const u16* wbase = whhf + ((size_t)(wave * 64) * 64 + lane) * 8;
  // LDS-resident frags (one-time copy; perf irrelevant here)
#pragma unroll
  for (int j = 0; j < F_LDS; ++j) {
    short8 v = *(const short8*)(wbase + (size_t)(F_REG + j) * 512);
    *(short8*)&wlds[(wave * F_LDS + j) * 512 + lane * 8] = v;
  }
  // register-resident frags
  short8 breg[F_REG];
#pragma unroll
  for (int F = 0; F < F_REG; ++F) breg[F] = *(const short8*)(wbase + (size_t)F * 512);

  float c_st[8] = {0.f, 0.f, 0.f, 0.f, 0.f, 0.f, 0.f, 0.f};
  __syncthreads();

  for (int t = 0; t < TT; ++t) {
    // streamed frags (L2-hot, same addr every step)
    short8 sbuf[F_STR];
#pragma unroll
    for (int s = 0; s < F_STR; ++s)
      sbuf[s] = *(const short8*)(wbase + (size_t)(F_REG + F_LDS + s) * 512);
    // xg for this step (consumed after MFMA phase -> latency hidden)
    const u16* xgp = xgf + (((size_t)(blockIdx.x * TT + t) * 8 + wave) * 64 + lane) * 32;
    short8 xv0 = *(const short8*)(xgp);
    short8 xv1 = *(const short8*)(xgp + 8);
    short8 xv2 = *(const short8*)(xgp + 16);
    short8 xv3 = *(const short8*)(xgp + 24);

    floatx4 acc[8];
#pragma unroll
    for (int tile = 0; tile < 8; ++tile) acc[tile] = (floatx4){0.f, 0.f, 0.f, 0.f};
#pragma unroll
    for (int kt = 0; kt < 8; ++kt) {
      short8 afr = *(const short8*)&hsw[l15 * 256 + (((kt * 4 + kq) ^ (l15 & 7)) << 3)];
#pragma unroll
      for (int tile = 0; tile < 8; ++tile) {
        const int F = kt * 8 + tile;
        short8 bfr;
        if (F < F_REG) bfr = breg[F];
        else if (F < F_REG + F_LDS)
          bfr = *(const short8*)&wlds[(wave * F_LDS + (F - F_REG)) * 512 + lane * 8];
        else bfr = sbuf[F - F_REG - F_LDS];
        acc[tile] = __builtin_amdgcn_mfma_f32_16x16x32_bf16(afr, bfr, acc[tile], 0, 0, 0);
      }
    }
    __syncthreads();   // all hsw reads done before overwrite

#pragma unroll
    for (int ht = 0; ht < 2; ++ht) {
      const int hd = wave * 32 + ht * 16 + l15;
#pragma unroll
      for (int rr = 0; rr < 4; ++rr) {
        // cell index c = tile*4+rr, tile = g*2+ht
        const int c0 = (0 + ht) * 4 + rr;
        const int c1 = (2 + ht) * 4 + rr;
        const int c2 = (4 + ht) * 4 + rr;
        const int c3 = (6 + ht) * 4 + rr;
        float x0 = b2f((u16)(c0 < 8 ? xv0[c0 & 7] : (c0 < 16 ? xv1[c0 & 7] : (c0 < 24 ? xv2[c0 & 7] : xv3[c0 & 7]))));
        float x1 = b2f((u16)(c1 < 8 ? xv0[c1 & 7] : (c1 < 16 ? xv1[c1 & 7] : (c1 < 24 ? xv2[c1 & 7] : xv3[c1 & 7]))));
        float x2 = b2f((u16)(c2 < 8 ? xv0[c2 & 7] : (c2 < 16 ? xv1[c2 & 7] : (c2 < 24 ? xv2[c2 & 7] : xv3[c2 & 7]))));
        float x3 = b2f((u16)(c3 < 8 ? xv0[c3 & 7] : (c3 < 16 ? xv1[c3 & 7] : (c3 < 24 ? xv2[c3 & 7] : xv3[c3 & 7]))));
        float iv = sigmf(acc[0 + ht][rr] + x0);
        float fv = sigmf(acc[2 + ht][rr] + x1);
        float gv = tanhfast(acc[4 + ht][rr] + x2);
        float ov = sigmf(acc[6 + ht][rr] + x3);
        const int ci = ht * 4 + rr;
        float cc = fv * c_st[ci] + iv * gv;
        c_st[ci] = cc;
        float h = ov * tanhfast(cc);
        u16 hb = f2b(h);
        const int m = kq * 4 + rr;
        hsw[m * 256 + (((hd >> 3) ^ (m & 7)) << 3) + (hd & 7)] = hb;
        hs[((size_t)(b0 + m) * TT + (size_t)t) * 256 + hd] = hb;
      }
    }
    __syncthreads();
  }
}

// ---------------- v1 fallback prep + scan ----------------

__global__ void k_prep_wcat(const float* __restrict__ wih, const float* __restrict__ whh,
                            u16* __restrict__ wcat) {
  int nrow = blockIdx.x, k = threadIdx.x;
  float v = 0.f;
  if (k < 43) v = wih[nrow * 43 + k];
  else if (k >= 64) v = whh[nrow * 256 + (k - 64)];
  wcat[nrow * 320 + k] = f2b(v);
}
__global__ void k_prep_xin(const float* __restrict__ x, u16* __restrict__ xin) {
  size_t idx = (size_t)blockIdx.x * 256 + threadIdx.x;
  size_t bt = idx >> 6;
  int d = (int)(idx & 63);
  int t = (int)(bt & 1023);
  float v = 0.f;
  if (d < 35) v = x[bt * 43 + d];
  else if (d < 43 && t > 0) v = x[(bt - 1) * 43 + d];
  xin[idx] = f2b(v);
}
__global__ __launch_bounds__(1024, 4)
void k_scan(const u16* __restrict__ wcat, const u16* __restrict__ xin,
            const float* __restrict__ bias, u16* __restrict__ hs) {
  __shared__ u16 xh[16 * XH_S];
  __shared__ float sbias[1024];
  const int tid = threadIdx.x;
  const int wave = tid >> 6;
  const int lane = tid & 63;
  const int l15 = lane & 15;
  const int kq = lane >> 4;
  const int b0 = blockIdx.x * 16;

  sbias[tid] = bias[tid];
  for (int i = tid; i < 16 * XH_S; i += 1024) xh[i] = 0;
  __syncthreads();
  if (tid < 512) {
    const int r = tid >> 5, c = tid & 31;
    *(u32*)&xh[r * XH_S + c * 2] =
        *(const u32*)(xin + (size_t)(b0 + r) * TT * KX + c * 2);
  }
  size_t boff[4];
  float bias_r[4];
#pragma unroll
  for (int g = 0; g < 4; ++g) {
    int n = g * 256 + wave * 16 + l15;
    boff[g] = (size_t)n * KTOT + (size_t)kq * 8;
    bias_r[g] = sbias[n];
  }
  __syncthreads();

  float c_st[4] = {0.f, 0.f, 0.f, 0.f};
  const int hd = wave * 16 + l15;
  const int ard = l15 * XH_S + kq * 8;

  for (int t = 0; t < TT; ++t) {
    floatx4 acc[4];
#pragma unroll
    for (int g = 0; g < 4; ++g) acc[g] = (floatx4){0.f, 0.f, 0.f, 0.f};
#pragma unroll
    for (int kt = 0; kt < 10; ++kt) {
      short8 afr = *(const short8*)&xh[ard + kt * 32];
#pragma unroll
      for (int g = 0; g < 4; ++g) {
        short8 bfr = *(const short8*)(wcat + boff[g] + kt * 32);
        acc[g] = __builtin_amdgcn_mfma_f32_16x16x32_bf16(afr, bfr, acc[g], 0, 0, 0);
      }
    }
    __syncthreads();
    u32 xv = 0;
    if (tid < 512 && t + 1 < TT) {
      const int r = tid >> 5, c = tid & 31;
      xv = *(const u32*)(xin + ((size_t)(b0 + r) * TT + (size_t)(t + 1)) * KX + c * 2);
    }
#pragma unroll
    for (int rr = 0; rr < 4; ++rr) {
      float iv = sigmf(acc[0][rr] + bias_r[0]);
      float fv = sigmf(acc[1][rr] + bias_r[1]);
      float gv = tanhfast(acc[2][rr] + bias_r[2]);
      float ov = sigmf(acc[3][rr] + bias_r[3]);
      float cc = fv * c_st[rr] + iv * gv;
      c_st[rr] = cc;
      float h = ov * tanhfast(cc);
      u16 hb = f2b(h);
      int m = kq * 4 + rr;
      xh[m * XH_S + KX + hd] = hb;
      hs[((size_t)(b0 + m) * TT + (size_t)t) * 256 + hd] = hb;
    }
    if (tid < 512 && t + 1 < TT) {
      const int r = tid >> 5, c = tid & 31;
      *(u32*)&xh[r * XH_S + c * 2] = xv;
    }
    __syncthreads();
  }
}

// ---------------- post heads (shared) ----------------

__global__ __launch_bounds__(256, 2)
void k_act(const u16* __restrict__ hs, const u16* __restrict__ wafc1,
           const u16* __restrict__ waout, const float* __restrict__ b_afc1,
           const float* __restrict__ b_aout, float* __restrict__ act) {
  __shared__ u16 a_sh[16 * 264];
  __shared__ u16 z_sh[16 * 264];
  __shared__ float sb1[256];
  const int tid = threadIdx.x;
  const int wave = tid >> 6, lane = tid & 63;
  const int l15 = lane & 15, kq = lane >> 4;
  const size_t bt0 = (size_t)blockIdx.x * 16;
  sb1[tid] = b_afc1[tid];
#pragma unroll
  for (int i = 0; i < 2; ++i) {
    int chunk = i * 256 + tid;
    int row = chunk >> 5, c = chunk & 31;
    *(uint4*)&a_sh[row * 264 + c * 8] = *(const uint4*)(hs + (bt0 + row) * 256 + c * 8);
  }
  __syncthreads();
  floatx4 acc[4];
#pragma unroll
  for (int nt = 0; nt < 4; ++nt) acc[nt] = (floatx4){0.f, 0.f, 0.f, 0.f};
#pragma unroll
  for (int kt = 0; kt < 8; ++kt) {
    short8 a = *(const short8*)&a_sh[l15 * 264 + kt * 32 + kq * 8];
#pragma unroll
    for (int nt = 0; nt < 4; ++nt) {
      int n = wave * 64 + nt * 16 + l15;
      short8 b = *(const short8*)(wafc1 + n * 256 + kt * 32 + kq * 8);
      acc[nt] = __builtin_amdgcn_mfma_f32_16x16x32_bf16(a, b, acc[nt], 0, 0, 0);
    }
  }
#pragma unroll
  for (int nt = 0; nt < 4; ++nt) {
    int n = wave * 64 + nt * 16 + l15;
    float bb = sb1[n];
#pragma unroll
    for (int r = 0; r < 4; ++r) {
      float v = acc[nt][r] + bb;
      v = v > 0.f ? v : 0.f;
      z_sh[(kq * 4 + r) * 264 + n] = f2b(v);
    }
  }
  __syncthreads();
  if (wave == 0) {
    floatx4 a2 = (floatx4){0.f, 0.f, 0.f, 0.f};
#pragma unroll
    for (int kt = 0; kt < 8; ++kt) {
      short8 a = *(const short8*)&z_sh[l15 * 264 + kt * 32 + kq * 8];
      short8 b = *(const short8*)(waout + l15 * 256 + kt * 32 + kq * 8);
      a2 = __builtin_amdgcn_mfma_f32_16x16x32_bf16(a, b, a2, 0, 0, 0);
    }
    if (l15 < 8) {
      float bb = b_aout[l15];
#pragma unroll
      for (int r = 0; r < 4; ++r)
        act[(bt0 + (size_t)(kq * 4 + r)) * 8 + l15] = a2[r] + bb;
    }
  }
}

__global__ __launch_bounds__(256, 2)
void k_cb(const u16* __restrict__ hs, const float* __restrict__ x,
          const u16* __restrict__ wcb, const float* __restrict__ b_cont,
          const float* __restrict__ b_bin, float* __restrict__ dout) {
  __shared__ u16 a_sh[16 * 296];
  const int tid = threadIdx.x;
  const int wave = tid >> 6, lane = tid & 63;
  const int l15 = lane & 15, kq = lane >> 4;
  const size_t bt0 = (size_t)blockIdx.x * 16;
#pragma unroll
  for (int i = 0; i < 2; ++i) {
    int chunk = i * 256 + tid;
    int row = chunk >> 5, c = chunk & 31;
    *(uint4*)&a_sh[row * 296 + c * 8] = *(const uint4*)(hs + (bt0 + row) * 256 + c * 8);
  }
  if (tid < 128) {
    int m = tid >> 3, j = tid & 7;
    a_sh[m * 296 + 256 + j] = f2b(x[(bt0 + m) * 43 + 35 + j]);
  }
  for (int i = tid; i < 384; i += 256) {
    int m = i / 24, jj = i % 24;
    a_sh[m * 296 + 264 + jj] = 0;
  }
  __syncthreads();
  const int n = wave * 16 + l15;
  floatx4 acc = (floatx4){0.f, 0.f, 0.f, 0.f};
#pragma unroll
  for (int kt = 0; kt < 9; ++kt) {
    short8 a = *(const short8*)&a_sh[l15 * 296 + kt * 32 + kq * 8];
    short8 b = *(const short8*)(wcb + n * 288 + kt * 32 + kq * 8);
    acc = __builtin_amdgcn_mfma_f32_16x16x32_bf16(a, b, acc, 0, 0, 0);
  }
  if (n < 50) {
    float bb = b_cont[n];
#pragma unroll
    for (int r = 0; r < 4; ++r)
      dout[(bt0 + (size_t)(kq * 4 + r)) * 50 + n] = acc[r] + bb;
  } else if (n < 60) {
    float bb = b_bin[n - 50];
#pragma unroll
    for (int r = 0; r < 4; ++r)
      dout[BIN_OFF + (bt0 + (size_t)(kq * 4 + r)) * 10 + (n - 50)] = sigmf(acc[r] + bb);
  }
}

// ---------------- launch ----------------
extern "C" void kernel_launch(void* const* d_in, const int* in_sizes, int n_in,
                              void* d_out, int out_size, void* d_ws, size_t ws_size,
                              hipStream_t stream) {
  const float* x      = (const float*)d_in[0];
  const float* W_ih   = (const float*)d_in[1];
  const float* W_hh   = (const float*)d_in[2];
  const float* b_ih   = (const float*)d_in[3];
  const float* b_hh   = (const float*)d_in[4];
  const float* W_afc1 = (const float*)d_in[5];
  const float* b_afc1 = (const float*)d_in[6];
  const float* W_aout = (const float*)d_in[7];
  const float* b_aout = (const float*)d_in[8];
  const float* W_cont = (const float*)d_in[9];
  const float* b_cont = (const float*)d_in[10];
  const float* W_bin  = (const float*)d_in[11];
  const float* b_bin  = (const float*)d_in[12];
  float* outf = (float*)d_out;
  char* ws = (char*)d_ws;

  if (ws_size >= 336379904ULL) {
    // xg path
    u16*   whhf   = (u16*)(ws);                    //    524,288 B
    float* bias   = (float*)(ws + 524288);         //      4,096 B
    u16*   wihp   = (u16*)(ws + 528384);           //    131,072 B
    u16*   wafc1b = (u16*)(ws + 659456);           //    131,072 B
    u16*   waoutb = (u16*)(ws + 790528);           //      8,192 B
    u16*   wcbb   = (u16*)(ws + 798720);           //     36,864 B
    u16*   hs     = (u16*)(ws + 835584);           // 67,108,864 B
    u16*   xgf    = (u16*)(ws + 67944448);         // 268,435,456 B -> 336,379,904

    hipLaunchKernelGGL(k_prep_bias, dim3(4), dim3(256), 0, stream, b_ih, b_hh, bias);
    hipLaunchKernelGGL(k_prep_whhf, dim3(1024), dim3(256), 0, stream, W_hh, whhf);
    hipLaunchKernelGGL(k_prep_wihp, dim3(256), dim3(256), 0, stream, W_ih, wihp);
    hipLaunchKernelGGL(k_prep_afc, dim3(272), dim3(256), 0, stream, W_afc1, W_aout, wafc1b, waoutb);
    hipLaunchKernelGGL(k_prep_wcb, dim3(64), dim3(288), 0, stream, W_cont, W_bin, wcbb);
    hipLaunchKernelGGL(k_xg, dim3(8192), dim3(512), 0, stream, x, wihp, bias, xgf);
    hipLaunchKernelGGL(k_scan2, dim3(8), dim3(512), 0, stream, whhf, xgf, hs);
    hipLaunchKernelGGL(k_act, dim3(8192), dim3(256), 0, stream, hs, wafc1b, waoutb, b_afc1, b_aout, outf + ACT_OFF);
    hipLaunchKernelGGL(k_cb, dim3(8192), dim3(256), 0, stream, hs, x, wcbb, b_cont, b_bin, outf);
  } else {
    // v1 fallback
    u16*   wcat   = (u16*)(ws);
    float* bias   = (float*)(ws + 655360);
    u16*   wafc1b = (u16*)(ws + 659456);
    u16*   waoutb = (u16*)(ws + 790528);
    u16*   wcbb   = (u16*)(ws + 798720);
    u16*   xin    = (u16*)(ws + 835584);
    u16*   hs     = (u16*)(ws + 17612800);

    hipLaunchKernelGGL(k_prep_wcat, dim3(1024), dim3(320), 0, stream, W_ih, W_hh, wcat);
    hipLaunchKernelGGL(k_prep_bias, dim3(4), dim3(256), 0, stream, b_ih, b_hh, bias);
    hipLaunchKernelGGL(k_prep_afc, dim3(272), dim3(256), 0, stream, W_afc1, W_aout, wafc1b, waoutb);
    hipLaunchKernelGGL(k_prep_wcb, dim3(64), dim3(288), 0, stream, W_cont, W_bin, wcbb);
    hipLaunchKernelGGL(k_prep_xin, dim3(32768), dim3(256), 0, stream, x, xin);
    hipLaunchKernelGGL(k_scan, dim3(8), dim3(1024), 0, stream, wcat, xin, bias, hs);
    hipLaunchKernelGGL(k_act, dim3(8192), dim3(256), 0, stream, hs, wafc1b, waoutb, b_afc1, b_aout, outf + ACT_OFF);
    hipLaunchKernelGGL(k_cb, dim3(8192), dim3(256), 0, stream, hs, x, wcbb, b_cont, b_bin, outf);
  }
}

// Round 3
// 9009.310 us; speedup vs baseline: 1.3154x; 1.3154x over previous
//
#include <hip/hip_runtime.h>

typedef unsigned int u32;
typedef unsigned short u16;
typedef __attribute__((ext_vector_type(8))) short short8;
typedef __attribute__((ext_vector_type(4))) float floatx4;

#define TT 1024
#define BIN_OFF 6553600
#define ACT_OFF 7864320

// scan3 weight residency tiers (per wave, 80 frags total, F = kt*8 + tile)
#define F_REG 38      // F 0..37   register-resident
#define F_LDS 12      // F 38..49  LDS-resident
#define F_STR 30      // F 50..79  streamed from L2 via global_load_lds each step

__device__ __forceinline__ u16 f2b(float f) {
  u32 u = __builtin_bit_cast(u32, f);
  u += 0x7fffu + ((u >> 16) & 1u);
  return (u16)(u >> 16);
}
__device__ __forceinline__ float sigmf(float x) { return 1.0f / (1.0f + __expf(-x)); }
__device__ __forceinline__ float tanhfast(float x) {
  x = fminf(x, 15.0f);
  float e = __expf(2.0f * x);
  return (e - 1.0f) / (e + 1.0f);
}
__device__ __forceinline__ void dma16(const void* g, void* l) {
  __builtin_amdgcn_global_load_lds(
      (const __attribute__((address_space(1))) u32*)g,
      (__attribute__((address_space(3))) u32*)l, 16, 0, 0);
}

// ---------------- prep ----------------

// bias = b_ih + b_hh.  grid 4 x 256
__global__ void k_prep_bias(const float* __restrict__ a, const float* __restrict__ b,
                            float* __restrict__ o) {
  int i = blockIdx.x * 256 + threadIdx.x;
  o[i] = a[i] + b[i];
}
// W_afc1 (256x256) and W_aout padded to 16x256.  grid 272 x 256
__global__ void k_prep_afc(const float* __restrict__ wafc1, const float* __restrict__ waout,
                           u16* __restrict__ ob1, u16* __restrict__ ob2) {
  int r = blockIdx.x, k = threadIdx.x;
  if (r < 256) ob1[r * 256 + k] = f2b(wafc1[r * 256 + k]);
  else {
    int y = r - 256;
    ob2[y * 256 + k] = f2b(y < 8 ? waout[y * 256 + k] : 0.f);
  }
}
// Wcb[64][288]: rows 0..49 W_cont, 50..59 W_bin.  grid 64 x 288
__global__ void k_prep_wcb(const float* __restrict__ wcont, const float* __restrict__ wbin,
                           u16* __restrict__ o) {
  int nrow = blockIdx.x, k = threadIdx.x;
  float v = 0.f;
  if (k < 264) {
    if (nrow < 50) v = wcont[nrow * 264 + k];
    else if (nrow < 60) v = wbin[(nrow - 50) * 264 + k];
  }
  o[nrow * 288 + k] = f2b(v);
}
// xin[b][t][64] bf16: d<35 -> x[b][t][d]; 35<=d<43 -> x[b][t-1][d]; else 0.  grid 32768 x 256
__global__ void k_prep_xin(const float* __restrict__ x, u16* __restrict__ xin) {
  size_t idx = (size_t)blockIdx.x * 256 + threadIdx.x;
  size_t bt = idx >> 6;
  int d = (int)(idx & 63);
  int t = (int)(bt & 1023);
  float v = 0.f;
  if (d < 35) v = x[bt * 43 + d];
  else if (d < 43 && t > 0) v = x[(bt - 1) * 43 + d];
  xin[idx] = f2b(v);
}
// Wcat fragment layout: o[((wave*80 + F)*64 + lane)*8 + j] = Wcat[n][k] bf16
// tile=F&7 (g=tile>>1, ht=tile&1), kt=F>>3; n=g*256+wave*32+ht*16+(lane&15);
// k=kt*32+(lane>>4)*8+j; Wcat = [x-pad64 | W_hh].  grid 1280 x 256
__global__ void k_prep_wcatf(const float* __restrict__ wih, const float* __restrict__ whh,
                             u16* __restrict__ o) {
  u32 idx = blockIdx.x * 256 + threadIdx.x;   // < 327680
  int j = idx & 7;
  int lane = (idx >> 3) & 63;
  u32 wfi = idx >> 9;                          // wave*80 + F, < 640
  int F = wfi % 80, wave = wfi / 80;
  int tile = F & 7, kt = F >> 3;
  int l15 = lane & 15, kq = lane >> 4;
  int n = (tile >> 1) * 256 + wave * 32 + (tile & 1) * 16 + l15;
  int k = kt * 32 + kq * 8 + j;
  float v = 0.f;
  if (k < 43) v = wih[n * 43 + k];
  else if (k >= 64) v = whh[n * 256 + (k - 64)];
  o[idx] = f2b(v);
}

// ---------------- LSTM scan v3 ----------------
// 8 WGs x 512 thr. WG owns batch rows [16g,16g+16). gates(16x1024) =
// [x_t|h](16x320) @ Wcat^T via mfma 16x16x32 bf16. Weights: 38 frags VGPR,
// 12 frags LDS, 30 frags DMA-streamed from L2 into 4-slot LDS ring (lookahead 3,
// explicit vmcnt waits). h/x tiles double-buffered + XOR-swizzled -> 1 barrier/step.
__global__ __launch_bounds__(512, 2)
void k_scan3(const u16* __restrict__ wcatf, const u16* __restrict__ xin,
             const float* __restrict__ bias, u16* __restrict__ hs) {
  __shared__ u16 wlds[8 * F_LDS * 512];   //  98304 B
  __shared__ u16 stag[8 * 4 * 512];       //  32768 B  (4-slot DMA ring per wave)
  __shared__ u16 hsw[2 * 16 * 256];       //  16384 B  (double-buffered swizzled h)
  __shared__ u16 xt[2 * 16 * 64];         //   4096 B  (double-buffered swizzled x)
  const int tid = threadIdx.x;            // total LDS 151552 B
  const int wave = tid >> 6, lane = tid & 63;
  const int l15 = lane & 15, kq = lane >> 4;
  const int b0 = blockIdx.x << 4;

  for (int i = tid; i < 4096; i += 512) hsw[i] = 0;

  const u16* wf = wcatf + (size_t)wave * 40960;   // this wave's 80 frags
  short8 breg[F_REG];
#pragma unroll
  for (int F = 0; F < F_REG; ++F)
    breg[F] = *(const short8*)(wf + (size_t)F * 512 + lane * 8);
#pragma unroll
  for (int q = 0; q < F_LDS; ++q)
    *(short8*)&wlds[(wave * F_LDS + q) * 512 + lane * 8] =
        *(const short8*)(wf + (size_t)(F_REG + q) * 512 + lane * 8);
  float bias_r[8];
#pragma unroll
  for (int tile = 0; tile < 8; ++tile) {
    int n = (tile >> 1) * 256 + wave * 32 + (tile & 1) * 16 + l15;
    bias_r[tile] = bias[n];
  }
  {  // x_0 -> xt[0], swizzled
    int r = tid >> 5, jj = tid & 31, ch = jj >> 2;
    u32 v = *(const u32*)(xin + (size_t)(b0 + r) * TT * 64 + jj * 2);
    *(u32*)&xt[r * 64 + ((ch ^ (r & 7)) * 8 + (jj & 3) * 2)] = v;
  }
  const char* wsg = (const char*)(wf + (size_t)(F_REG + F_LDS) * 512) + lane * 16;
  u16* st_base = &stag[wave * 4 * 512];
  const u16* xrp = xin + (size_t)(b0 + (tid >> 5)) * TT * 64 + (tid & 31) * 2;
  u16* hp = hs + ((size_t)(b0 + kq * 4) * TT) * 256 + wave * 32 + l15;

  float c_st[8];
#pragma unroll
  for (int i = 0; i < 8; ++i) c_st[i] = 0.f;
  u16 h8[8];
  __syncthreads();

  for (int t = 0; t < TT; ++t) {
    const int cur = t & 1, nxt = cur ^ 1;
    if (t > 0) {  // deferred hs stores for t-1 (drain overlaps this step)
#pragma unroll
      for (int ht = 0; ht < 2; ++ht)
#pragma unroll
        for (int rr = 0; rr < 4; ++rr)
          hp[(size_t)rr * TT * 256 + (size_t)(t - 1) * 256 + ht * 16] = h8[ht * 4 + rr];
    }
    u32 xv = 0;
    if (t + 1 < TT) xv = *(const u32*)(xrp + (size_t)(t + 1) * 64);
    // prime stream ring: s = 0,1,2
    dma16(wsg + 0 * 1024, st_base + 0 * 512);
    dma16(wsg + 1 * 1024, st_base + 1 * 512);
    dma16(wsg + 2 * 1024, st_base + 2 * 512);

    floatx4 acc[8];
#pragma unroll
    for (int i = 0; i < 8; ++i) acc[i] = (floatx4){0.f, 0.f, 0.f, 0.f};

#pragma unroll
    for (int kt = 0; kt < 10; ++kt) {
      short8 afr;
      if (kt < 2) {
        int ch = kt * 4 + kq;
        afr = *(const short8*)&xt[cur * 1024 + l15 * 64 + ((ch ^ (l15 & 7)) * 8)];
      } else {
        int ch = (kt - 2) * 4 + kq;
        afr = *(const short8*)&hsw[cur * 4096 + l15 * 256 + ((ch ^ (l15 & 7)) * 8)];
      }
#pragma unroll
      for (int tile = 0; tile < 8; ++tile) {
        const int F = kt * 8 + tile;
        short8 bfr;
        if (F < F_REG) {
          bfr = breg[F];
        } else if (F < F_REG + F_LDS) {
          bfr = *(const short8*)&wlds[(wave * F_LDS + (F - F_REG)) * 512 + lane * 8];
        } else {
          const int s = F - (F_REG + F_LDS);          // 0..29, compile-time
          if (s + 3 < F_STR)
            dma16(wsg + (size_t)(s + 3) * 1024, st_base + ((s + 3) % 4) * 512);
          // wait for DMA s: >= min(3, 29-s) newer DMAs guaranteed outstanding
          if (s == 29)      asm volatile("s_waitcnt vmcnt(0)" ::: "memory");
          else if (s == 28) asm volatile("s_waitcnt vmcnt(1)" ::: "memory");
          else if (s == 27) asm volatile("s_waitcnt vmcnt(2)" ::: "memory");
          else              asm volatile("s_waitcnt vmcnt(3)" ::: "memory");
          bfr = *(const short8*)&stag[(wave * 4 + (s % 4)) * 512 + lane * 8];
        }
        acc[tile] = __builtin_amdgcn_mfma_f32_16x16x32_bf16(afr, bfr, acc[tile], 0, 0, 0);
      }
    }

#pragma unroll
    for (int ht = 0; ht < 2; ++ht) {
      const int hd = wave * 32 + ht * 16 + l15;
      const int hch = hd >> 3;
#pragma unroll
      for (int rr = 0; rr < 4; ++rr) {  // C-layout: row m=kq*4+rr, col hd
        float iv = sigmf(acc[0 + ht][rr] + bias_r[0 + ht]);
        float fv = sigmf(acc[2 + ht][rr] + bias_r[2 + ht]);
        float gv = tanhfast(acc[4 + ht][rr] + bias_r[4 + ht]);
        float ov = sigmf(acc[6 + ht][rr] + bias_r[6 + ht]);
        const int ci = ht * 4 + rr;
        float cc = fv * c_st[ci] + iv * gv;
        c_st[ci] = cc;
        float h = ov * tanhfast(cc);
        u16 hb = f2b(h);
        h8[ci] = hb;
        const int m = kq * 4 + rr;
        hsw[nxt * 4096 + m * 256 + ((hch ^ (m & 7)) * 8) + (hd & 7)] = hb;
      }
    }
    if (t + 1 < TT) {
      int r = tid >> 5, jj = tid & 31, ch = jj >> 2;
      *(u32*)&xt[nxt * 1024 + r * 64 + ((ch ^ (r & 7)) * 8 + (jj & 3) * 2)] = xv;
    }
    __syncthreads();
  }
#pragma unroll
  for (int ht = 0; ht < 2; ++ht)
#pragma unroll
    for (int rr = 0; rr < 4; ++rr)
      hp[(size_t)rr * TT * 256 + (size_t)(TT - 1) * 256 + ht * 16] = h8[ht * 4 + rr];
}

// ---------------- post heads ----------------

__global__ __launch_bounds__(256, 2)
void k_act(const u16* __restrict__ hs, const u16* __restrict__ wafc1,
           const u16* __restrict__ waout, const float* __restrict__ b_afc1,
           const float* __restrict__ b_aout, float* __restrict__ act) {
  __shared__ u16 a_sh[16 * 264];
  __shared__ u16 z_sh[16 * 264];
  __shared__ float sb1[256];
  const int tid = threadIdx.x;
  const int wave = tid >> 6, lane = tid & 63;
  const int l15 = lane & 15, kq = lane >> 4;
  const size_t bt0 = (size_t)blockIdx.x * 16;
  sb1[tid] = b_afc1[tid];
#pragma unroll
  for (int i = 0; i < 2; ++i) {
    int chunk = i * 256 + tid;
    int row = chunk >> 5, c = chunk & 31;
    *(uint4*)&a_sh[row * 264 + c * 8] = *(const uint4*)(hs + (bt0 + row) * 256 + c * 8);
  }
  __syncthreads();
  floatx4 acc[4];
#pragma unroll
  for (int nt = 0; nt < 4; ++nt) acc[nt] = (floatx4){0.f, 0.f, 0.f, 0.f};
#pragma unroll
  for (int kt = 0; kt < 8; ++kt) {
    short8 a = *(const short8*)&a_sh[l15 * 264 + kt * 32 + kq * 8];
#pragma unroll
    for (int nt = 0; nt < 4; ++nt) {
      int n = wave * 64 + nt * 16 + l15;
      short8 b = *(const short8*)(wafc1 + n * 256 + kt * 32 + kq * 8);
      acc[nt] = __builtin_amdgcn_mfma_f32_16x16x32_bf16(a, b, acc[nt], 0, 0, 0);
    }
  }
#pragma unroll
  for (int nt = 0; nt < 4; ++nt) {
    int n = wave * 64 + nt * 16 + l15;
    float bb = sb1[n];
#pragma unroll
    for (int r = 0; r < 4; ++r) {
      float v = acc[nt][r] + bb;
      v = v > 0.f ? v : 0.f;
      z_sh[(kq * 4 + r) * 264 + n] = f2b(v);
    }
  }
  __syncthreads();
  if (wave == 0) {
    floatx4 a2 = (floatx4){0.f, 0.f, 0.f, 0.f};
#pragma unroll
    for (int kt = 0; kt < 8; ++kt) {
      short8 a = *(const short8*)&z_sh[l15 * 264 + kt * 32 + kq * 8];
      short8 b = *(const short8*)(waout + l15 * 256 + kt * 32 + kq * 8);
      a2 = __builtin_amdgcn_mfma_f32_16x16x32_bf16(a, b, a2, 0, 0, 0);
    }
    if (l15 < 8) {
      float bb = b_aout[l15];
#pragma unroll
      for (int r = 0; r < 4; ++r)
        act[(bt0 + (size_t)(kq * 4 + r)) * 8 + l15] = a2[r] + bb;
    }
  }
}

__global__ __launch_bounds__(256, 2)
void k_cb(const u16* __restrict__ hs, const float* __restrict__ x,
          const u16* __restrict__ wcb, const float* __restrict__ b_cont,
          const float* __restrict__ b_bin, float* __restrict__ dout) {
  __shared__ u16 a_sh[16 * 296];
  const int tid = threadIdx.x;
  const int wave = tid >> 6, lane = tid & 63;
  const int l15 = lane & 15, kq = lane >> 4;
  const size_t bt0 = (size_t)blockIdx.x * 16;
#pragma unroll
  for (int i = 0; i < 2; ++i) {
    int chunk = i * 256 + tid;
    int row = chunk >> 5, c = chunk & 31;
    *(uint4*)&a_sh[row * 296 + c * 8] = *(const uint4*)(hs + (bt0 + row) * 256 + c * 8);
  }
  if (tid < 128) {
    int m = tid >> 3, j = tid & 7;
    a_sh[m * 296 + 256 + j] = f2b(x[(bt0 + m) * 43 + 35 + j]);
  }
  for (int i = tid; i < 384; i += 256) {
    int m = i / 24, jj = i % 24;
    a_sh[m * 296 + 264 + jj] = 0;
  }
  __syncthreads();
  const int n = wave * 16 + l15;
  floatx4 acc = (floatx4){0.f, 0.f, 0.f, 0.f};
#pragma unroll
  for (int kt = 0; kt < 9; ++kt) {
    short8 a = *(const short8*)&a_sh[l15 * 296 + kt * 32 + kq * 8];
    short8 b = *(const short8*)(wcb + n * 288 + kt * 32 + kq * 8);
    acc = __builtin_amdgcn_mfma_f32_16x16x32_bf16(a, b, acc, 0, 0, 0);
  }
  if (n < 50) {
    float bb = b_cont[n];
#pragma unroll
    for (int r = 0; r < 4; ++r)
      dout[(bt0 + (size_t)(kq * 4 + r)) * 50 + n] = acc[r] + bb;
  } else if (n < 60) {
    float bb = b_bin[n - 50];
#pragma unroll
    for (int r = 0; r < 4; ++r)
      dout[BIN_OFF + (bt0 + (size_t)(kq * 4 + r)) * 10 + (n - 50)] = sigmf(acc[r] + bb);
  }
}

// ---------------- launch ----------------
extern "C" void kernel_launch(void* const* d_in, const int* in_sizes, int n_in,
                              void* d_out, int out_size, void* d_ws, size_t ws_size,
                              hipStream_t stream) {
  const float* x      = (const float*)d_in[0];
  const float* W_ih   = (const float*)d_in[1];
  const float* W_hh   = (const float*)d_in[2];
  const float* b_ih   = (const float*)d_in[3];
  const float* b_hh   = (const float*)d_in[4];
  const float* W_afc1 = (const float*)d_in[5];
  const float* b_afc1 = (const float*)d_in[6];
  const float* W_aout = (const float*)d_in[7];
  const float* b_aout = (const float*)d_in[8];
  const float* W_cont = (const float*)d_in[9];
  const float* b_cont = (const float*)d_in[10];
  const float* W_bin  = (const float*)d_in[11];
  const float* b_bin  = (const float*)d_in[12];
  float* outf = (float*)d_out;
  char* ws = (char*)d_ws;

  u16*   wcatf  = (u16*)(ws);                    //    655,360 B
  float* bias   = (float*)(ws + 655360);         //      4,096 B
  u16*   wafc1b = (u16*)(ws + 659456);           //    131,072 B
  u16*   waoutb = (u16*)(ws + 790528);           //      8,192 B
  u16*   wcbb   = (u16*)(ws + 798720);           //     36,864 B
  u16*   xin    = (u16*)(ws + 835584);           // 16,777,216 B
  u16*   hs     = (u16*)(ws + 17612800);         // 67,108,864 B  (total ~84.7 MB)

  hipLaunchKernelGGL(k_prep_wcatf, dim3(1280), dim3(256), 0, stream, W_ih, W_hh, wcatf);
  hipLaunchKernelGGL(k_prep_bias, dim3(4), dim3(256), 0, stream, b_ih, b_hh, bias);
  hipLaunchKernelGGL(k_prep_afc, dim3(272), dim3(256), 0, stream, W_afc1, W_aout, wafc1b, waoutb);
  hipLaunchKernelGGL(k_prep_wcb, dim3(64), dim3(288), 0, stream, W_cont, W_bin, wcbb);
  hipLaunchKernelGGL(k_prep_xin, dim3(32768), dim3(256), 0, stream, x, xin);
  hipLaunchKernelGGL(k_scan3, dim3(8), dim3(512), 0, stream, wcatf, xin, bias, hs);
  hipLaunchKernelGGL(k_act, dim3(8192), dim3(256), 0, stream, hs, wafc1b, waoutb, b_afc1, b_aout, outf + ACT_OFF);
  hipLaunchKernelGGL(k_cb, dim3(8192), dim3(256), 0, stream, hs, x, wcbb, b_cont, b_bin, outf);
}

// Round 4
// 4169.426 us; speedup vs baseline: 2.8424x; 2.1608x over previous
//
#include <hip/hip_runtime.h>

typedef unsigned int u32;
typedef unsigned short u16;
typedef unsigned long long u64;
typedef __attribute__((ext_vector_type(8))) short short8;
typedef __attribute__((ext_vector_type(4))) float floatx4;

#define TT 1024
#define BIN_OFF 6553600
#define ACT_OFF 7864320

// scan4: per-wave 40 frags (F = kt*4 + gate), all resident
#define F_REG4 24     // F 0..23 in VGPRs (96 regs)
#define F_LDS4 16     // F 24..39 in LDS (8 waves * 16 KB = 128 KB)

__device__ __forceinline__ u16 f2b(float f) {
  u32 u = __builtin_bit_cast(u32, f);
  u += 0x7fffu + ((u >> 16) & 1u);
  return (u16)(u >> 16);
}
__device__ __forceinline__ float sigmf(float x) { return 1.0f / (1.0f + __expf(-x)); }
__device__ __forceinline__ float tanhfast(float x) {
  x = fminf(x, 15.0f);
  float e = __expf(2.0f * x);
  return (e - 1.0f) / (e + 1.0f);
}

// ---------------- prep ----------------

__global__ void k_zero_flags(u32* __restrict__ flags) {
  if (threadIdx.x < 16) flags[threadIdx.x] = 0;
}
// bias = b_ih + b_hh.  grid 4 x 256
__global__ void k_prep_bias(const float* __restrict__ a, const float* __restrict__ b,
                            float* __restrict__ o) {
  int i = blockIdx.x * 256 + threadIdx.x;
  o[i] = a[i] + b[i];
}
// W_afc1 (256x256) and W_aout padded to 16x256.  grid 272 x 256
__global__ void k_prep_afc(const float* __restrict__ wafc1, const float* __restrict__ waout,
                           u16* __restrict__ ob1, u16* __restrict__ ob2) {
  int r = blockIdx.x, k = threadIdx.x;
  if (r < 256) ob1[r * 256 + k] = f2b(wafc1[r * 256 + k]);
  else {
    int y = r - 256;
    ob2[y * 256 + k] = f2b(y < 8 ? waout[y * 256 + k] : 0.f);
  }
}
// Wcb[64][288]: rows 0..49 W_cont, 50..59 W_bin.  grid 64 x 288
__global__ void k_prep_wcb(const float* __restrict__ wcont, const float* __restrict__ wbin,
                           u16* __restrict__ o) {
  int nrow = blockIdx.x, k = threadIdx.x;
  float v = 0.f;
  if (k < 264) {
    if (nrow < 50) v = wcont[nrow * 264 + k];
    else if (nrow < 60) v = wbin[(nrow - 50) * 264 + k];
  }
  o[nrow * 288 + k] = f2b(v);
}
// xin[b][t][64] bf16.  grid 32768 x 256
__global__ void k_prep_xin(const float* __restrict__ x, u16* __restrict__ xin) {
  size_t idx = (size_t)blockIdx.x * 256 + threadIdx.x;
  size_t bt = idx >> 6;
  int d = (int)(idx & 63);
  int t = (int)(bt & 1023);
  float v = 0.f;
  if (d < 35) v = x[bt * 43 + d];
  else if (d < 43 && t > 0) v = x[(bt - 1) * 43 + d];
  xin[idx] = f2b(v);
}
// scan4 frag layout: o[(((hf*8+wave)*40 + F)*64 + lane)*8 + j], F = kt*4+gate;
// n = gate*256 + hf*128 + wave*16 + (lane&15); k = kt*32 + (lane>>4)*8 + j.
// grid 1280 x 256 (327680 elems)
__global__ void k_prep_wcatf2(const float* __restrict__ wih, const float* __restrict__ whh,
                              u16* __restrict__ o) {
  u32 idx = blockIdx.x * 256 + threadIdx.x;
  int j = idx & 7;
  int lane = (idx >> 3) & 63;
  u32 wf = idx >> 9;                  // (hf*8+wave)*40 + F, < 640
  int F = wf % 40, wv = wf / 40;      // wv = hf*8+wave
  int gate = F & 3, kt = F >> 2;
  int l15 = lane & 15, kq = lane >> 4;
  int n = gate * 256 + (wv >> 3) * 128 + (wv & 7) * 16 + l15;
  int k = kt * 32 + kq * 8 + j;
  float v = 0.f;
  if (k < 43) v = wih[n * 43 + k];
  else if (k >= 64) v = whh[n * 256 + (k - 64)];
  o[idx] = f2b(v);
}

// ---------------- LSTM scan v4: N-split pairs ----------------
// 16 WGs x 512 thr. WG g: pair p=g&7 (batch rows 16p..16p+15), half hf=g>>3
// (h-cols hf*128..+127). All weights resident (24 frags VGPR + 16 frags LDS per
// wave). Per step: 40 MFMA/wave; halves exchange 4 KB of h via device-coherent
// atomics + monotone flags (parity double-buffered, lockstep +-1 safe).
__global__ __launch_bounds__(512)
void k_scan4(const u16* __restrict__ wcatf, const u16* __restrict__ xin,
             const float* __restrict__ bias, u16* __restrict__ hs,
             u16* __restrict__ xchg, u32* __restrict__ flags) {
  __shared__ u16 wlds[8 * F_LDS4 * 512];  // 131072 B
  __shared__ u16 hsw[2 * 16 * 256];       //  16384 B (double-buffered swizzled h)
  __shared__ u16 xt[2 * 16 * 64];         //   4096 B (double-buffered swizzled x)
  const int tid = threadIdx.x;            // total LDS 151552 B
  const int wave = tid >> 6, lane = tid & 63;
  const int l15 = lane & 15, kq = lane >> 4;
  const int g = blockIdx.x;
  const int p = g & 7, hf = g >> 3;
  const int partner = g ^ 8;
  const int b0 = p * 16;

  for (int i = tid; i < 8192; i += 512) hsw[i] = 0;

  const u16* wbase = wcatf + (size_t)((hf * 8 + wave) * 40) * 512;
  short8 breg[F_REG4];
#pragma unroll
  for (int F = 0; F < F_REG4; ++F)
    breg[F] = *(const short8*)(wbase + (size_t)F * 512 + lane * 8);
#pragma unroll
  for (int q = 0; q < F_LDS4; ++q)
    *(short8*)&wlds[(wave * F_LDS4 + q) * 512 + lane * 8] =
        *(const short8*)(wbase + (size_t)(F_REG4 + q) * 512 + lane * 8);
  float bias_r[4];
#pragma unroll
  for (int gate = 0; gate < 4; ++gate)
    bias_r[gate] = bias[gate * 256 + hf * 128 + wave * 16 + l15];
  {  // x_0 -> xt[0], swizzled
    int r = tid >> 5, jj = tid & 31, ch = jj >> 2;
    u32 v = *(const u32*)(xin + (size_t)(b0 + r) * TT * 64 + jj * 2);
    *(u32*)&xt[r * 64 + ((ch ^ (r & 7)) * 8 + (jj & 3) * 2)] = v;
  }
  const u16* xrp = xin + (size_t)(b0 + (tid >> 5)) * TT * 64 + (tid & 31) * 2;
  const int hd = wave * 16 + l15;        // local col 0..127
  const int gcol = hf * 128 + hd;        // global h col
  u16* hp = hs + ((size_t)(b0 + kq * 4) * TT) * 256 + gcol;
  u64* mybuf0 = (u64*)(xchg + (size_t)(g * 2) * 2048) + (hd * 16 + kq * 4) / 4;
  const u64* pbuf0 = (u64*)(xchg + (size_t)(partner * 2) * 2048) + tid;

  float c_st[4] = {0.f, 0.f, 0.f, 0.f};
  __syncthreads();

  for (int t = 0; t < TT; ++t) {
    const int cur = t & 1, nxt = cur ^ 1;
    u32 xv = 0;
    if (t + 1 < TT) xv = *(const u32*)(xrp + (size_t)(t + 1) * 64);

    floatx4 acc[4];
#pragma unroll
    for (int i = 0; i < 4; ++i) acc[i] = (floatx4){0.f, 0.f, 0.f, 0.f};
#pragma unroll
    for (int kt = 0; kt < 10; ++kt) {
      short8 afr;
      if (kt < 2) {
        int ch = kt * 4 + kq;
        afr = *(const short8*)&xt[cur * 1024 + l15 * 64 + ((ch ^ (l15 & 7)) * 8)];
      } else {
        int ch = (kt - 2) * 4 + kq;
        afr = *(const short8*)&hsw[cur * 4096 + l15 * 256 + ((ch ^ (l15 & 7)) * 8)];
      }
#pragma unroll
      for (int gate = 0; gate < 4; ++gate) {
        const int F = kt * 4 + gate;
        short8 bfr;
        if (F < F_REG4) bfr = breg[F];
        else bfr = *(const short8*)&wlds[(wave * F_LDS4 + (F - F_REG4)) * 512 + lane * 8];
        acc[gate] = __builtin_amdgcn_mfma_f32_16x16x32_bf16(afr, bfr, acc[gate], 0, 0, 0);
      }
    }

    u16 hb[4];
#pragma unroll
    for (int rr = 0; rr < 4; ++rr) {     // C-layout: row m=kq*4+rr, col gcol
      float iv = sigmf(acc[0][rr] + bias_r[0]);
      float fv = sigmf(acc[1][rr] + bias_r[1]);
      float gv = tanhfast(acc[2][rr] + bias_r[2]);
      float ov = sigmf(acc[3][rr] + bias_r[3]);
      float cc = fv * c_st[rr] + iv * gv;
      c_st[rr] = cc;
      float h = ov * tanhfast(cc);
      hb[rr] = f2b(h);
      const int m = kq * 4 + rr;
      hsw[nxt * 4096 + m * 256 + (((gcol >> 3) ^ (m & 7)) << 3) + (gcol & 7)] = hb[rr];
      hp[(size_t)rr * TT * 256 + (size_t)t * 256] = hb[rr];
    }
    if (t + 1 < TT) {
      u64 pk = (u64)hb[0] | ((u64)hb[1] << 16) | ((u64)hb[2] << 32) | ((u64)hb[3] << 48);
      __hip_atomic_store(mybuf0 + (size_t)cur * 512, pk,
                         __ATOMIC_RELAXED, __HIP_MEMORY_SCOPE_AGENT);
    }
    asm volatile("s_waitcnt vmcnt(0)" ::: "memory");
    __syncthreads();
    if (t + 1 < TT) {
      if (tid == 0) {
        __hip_atomic_store(&flags[g], (u32)(t + 1),
                           __ATOMIC_RELEASE, __HIP_MEMORY_SCOPE_AGENT);
        while (__hip_atomic_load(&flags[partner], __ATOMIC_ACQUIRE,
                                 __HIP_MEMORY_SCOPE_AGENT) < (u32)(t + 1)) {}
      }
      __syncthreads();
      // read partner half: thread -> col=tid>>2 (0..127), q4=tid&3 (row group)
      u64 pv = __hip_atomic_load(pbuf0 + (size_t)cur * 512,
                                 __ATOMIC_RELAXED, __HIP_MEMORY_SCOPE_AGENT);
      const int pcol = (hf ^ 1) * 128 + (tid >> 2);
      const int q4 = tid & 3;
#pragma unroll
      for (int r2 = 0; r2 < 4; ++r2) {
        const int m = q4 * 4 + r2;
        hsw[nxt * 4096 + m * 256 + (((pcol >> 3) ^ (m & 7)) << 3) + (pcol & 7)] =
            (u16)(pv >> (16 * r2));
      }
      int r = tid >> 5, jj = tid & 31, ch = jj >> 2;
      *(u32*)&xt[nxt * 1024 + r * 64 + ((ch ^ (r & 7)) * 8 + (jj & 3) * 2)] = xv;
    }
    __syncthreads();
  }
}

// ---------------- post heads ----------------

__global__ __launch_bounds__(256, 2)
void k_act(const u16* __restrict__ hs, const u16* __restrict__ wafc1,
           const u16* __restrict__ waout, const float* __restrict__ b_afc1,
           const float* __restrict__ b_aout, float* __restrict__ act) {
  __shared__ u16 a_sh[16 * 264];
  __shared__ u16 z_sh[16 * 264];
  __shared__ float sb1[256];
  const int tid = threadIdx.x;
  const int wave = tid >> 6, lane = tid & 63;
  const int l15 = lane & 15, kq = lane >> 4;
  const size_t bt0 = (size_t)blockIdx.x * 16;
  sb1[tid] = b_afc1[tid];
#pragma unroll
  for (int i = 0; i < 2; ++i) {
    int chunk = i * 256 + tid;
    int row = chunk >> 5, c = chunk & 31;
    *(uint4*)&a_sh[row * 264 + c * 8] = *(const uint4*)(hs + (bt0 + row) * 256 + c * 8);
  }
  __syncthreads();
  floatx4 acc[4];
#pragma unroll
  for (int nt = 0; nt < 4; ++nt) acc[nt] = (floatx4){0.f, 0.f, 0.f, 0.f};
#pragma unroll
  for (int kt = 0; kt < 8; ++kt) {
    short8 a = *(const short8*)&a_sh[l15 * 264 + kt * 32 + kq * 8];
#pragma unroll
    for (int nt = 0; nt < 4; ++nt) {
      int n = wave * 64 + nt * 16 + l15;
      short8 b = *(const short8*)(wafc1 + n * 256 + kt * 32 + kq * 8);
      acc[nt] = __builtin_amdgcn_mfma_f32_16x16x32_bf16(a, b, acc[nt], 0, 0, 0);
    }
  }
#pragma unroll
  for (int nt = 0; nt < 4; ++nt) {
    int n = wave * 64 + nt * 16 + l15;
    float bb = sb1[n];
#pragma unroll
    for (int r = 0; r < 4; ++r) {
      float v = acc[nt][r] + bb;
      v = v > 0.f ? v : 0.f;
      z_sh[(kq * 4 + r) * 264 + n] = f2b(v);
    }
  }
  __syncthreads();
  if (wave == 0) {
    floatx4 a2 = (floatx4){0.f, 0.f, 0.f, 0.f};
#pragma unroll
    for (int kt = 0; kt < 8; ++kt) {
      short8 a = *(const short8*)&z_sh[l15 * 264 + kt * 32 + kq * 8];
      short8 b = *(const short8*)(waout + l15 * 256 + kt * 32 + kq * 8);
      a2 = __builtin_amdgcn_mfma_f32_16x16x32_bf16(a, b, a2, 0, 0, 0);
    }
    if (l15 < 8) {
      float bb = b_aout[l15];
#pragma unroll
      for (int r = 0; r < 4; ++r)
        act[(bt0 + (size_t)(kq * 4 + r)) * 8 + l15] = a2[r] + bb;
    }
  }
}

__global__ __launch_bounds__(256, 2)
void k_cb(const u16* __restrict__ hs, const float* __restrict__ x,
          const u16* __restrict__ wcb, const float* __restrict__ b_cont,
          const float* __restrict__ b_bin, float* __restrict__ dout) {
  __shared__ u16 a_sh[16 * 296];
  const int tid = threadIdx.x;
  const int wave = tid >> 6, lane = tid & 63;
  const int l15 = lane & 15, kq = lane >> 4;
  const size_t bt0 = (size_t)blockIdx.x * 16;
#pragma unroll
  for (int i = 0; i < 2; ++i) {
    int chunk = i * 256 + tid;
    int row = chunk >> 5, c = chunk & 31;
    *(uint4*)&a_sh[row * 296 + c * 8] = *(const uint4*)(hs + (bt0 + row) * 256 + c * 8);
  }
  if (tid < 128) {
    int m = tid >> 3, j = tid & 7;
    a_sh[m * 296 + 256 + j] = f2b(x[(bt0 + m) * 43 + 35 + j]);
  }
  for (int i = tid; i < 384; i += 256) {
    int m = i / 24, jj = i % 24;
    a_sh[m * 296 + 264 + jj] = 0;
  }
  __syncthreads();
  const int n = wave * 16 + l15;
  floatx4 acc = (floatx4){0.f, 0.f, 0.f, 0.f};
#pragma unroll
  for (int kt = 0; kt < 9; ++kt) {
    short8 a = *(const short8*)&a_sh[l15 * 296 + kt * 32 + kq * 8];
    short8 b = *(const short8*)(wcb + n * 288 + kt * 32 + kq * 8);
    acc = __builtin_amdgcn_mfma_f32_16x16x32_bf16(a, b, acc, 0, 0, 0);
  }
  if (n < 50) {
    float bb = b_cont[n];
#pragma unroll
    for (int r = 0; r < 4; ++r)
      dout[(bt0 + (size_t)(kq * 4 + r)) * 50 + n] = acc[r] + bb;
  } else if (n < 60) {
    float bb = b_bin[n - 50];
#pragma unroll
    for (int r = 0; r < 4; ++r)
      dout[BIN_OFF + (bt0 + (size_t)(kq * 4 + r)) * 10 + (n - 50)] = sigmf(acc[r] + bb);
  }
}

// ---------------- launch ----------------
extern "C" void kernel_launch(void* const* d_in, const int* in_sizes, int n_in,
                              void* d_out, int out_size, void* d_ws, size_t ws_size,
                              hipStream_t stream) {
  const float* x      = (const float*)d_in[0];
  const float* W_ih   = (const float*)d_in[1];
  const float* W_hh   = (const float*)d_in[2];
  const float* b_ih   = (const float*)d_in[3];
  const float* b_hh   = (const float*)d_in[4];
  const float* W_afc1 = (const float*)d_in[5];
  const float* b_afc1 = (const float*)d_in[6];
  const float* W_aout = (const float*)d_in[7];
  const float* b_aout = (const float*)d_in[8];
  const float* W_cont = (const float*)d_in[9];
  const float* b_cont = (const float*)d_in[10];
  const float* W_bin  = (const float*)d_in[11];
  const float* b_bin  = (const float*)d_in[12];
  float* outf = (float*)d_out;
  char* ws = (char*)d_ws;

  u16*   wcatf  = (u16*)(ws);                    //    655,360 B
  float* bias   = (float*)(ws + 655360);         //      4,096 B
  u16*   wafc1b = (u16*)(ws + 659456);           //    131,072 B
  u16*   waoutb = (u16*)(ws + 790528);           //      8,192 B
  u16*   wcbb   = (u16*)(ws + 798720);           //     36,864 B
  u16*   xchg   = (u16*)(ws + 835584);           //    131,072 B
  u32*   flags  = (u32*)(ws + 966656);           //      4,096 B
  u16*   xin    = (u16*)(ws + 970752);           // 16,777,216 B
  u16*   hs     = (u16*)(ws + 17747968);         // 67,108,864 B (total ~84.9 MB)

  hipLaunchKernelGGL(k_prep_wcatf2, dim3(1280), dim3(256), 0, stream, W_ih, W_hh, wcatf);
  hipLaunchKernelGGL(k_zero_flags, dim3(1), dim3(64), 0, stream, flags);
  hipLaunchKernelGGL(k_prep_bias, dim3(4), dim3(256), 0, stream, b_ih, b_hh, bias);
  hipLaunchKernelGGL(k_prep_afc, dim3(272), dim3(256), 0, stream, W_afc1, W_aout, wafc1b, waoutb);
  hipLaunchKernelGGL(k_prep_wcb, dim3(64), dim3(288), 0, stream, W_cont, W_bin, wcbb);
  hipLaunchKernelGGL(k_prep_xin, dim3(32768), dim3(256), 0, stream, x, xin);
  hipLaunchKernelGGL(k_scan4, dim3(16), dim3(512), 0, stream, wcatf, xin, bias, hs, xchg, flags);
  hipLaunchKernelGGL(k_act, dim3(8192), dim3(256), 0, stream, hs, wafc1b, waoutb, b_afc1, b_aout, outf + ACT_OFF);
  hipLaunchKernelGGL(k_cb, dim3(8192), dim3(256), 0, stream, hs, x, wcbb, b_cont, b_bin, outf);
}